// Round 11
// baseline (170.887 us; speedup 1.0000x reference)
//
#include <hip/hip_runtime.h>
#include <hip/hip_bf16.h>

typedef __attribute__((ext_vector_type(8))) short short8;
typedef __attribute__((ext_vector_type(2))) float f32x2;
typedef __attribute__((ext_vector_type(16))) float f32x16;
typedef __attribute__((ext_vector_type(4))) unsigned int uint4v;
typedef unsigned short ushort_t;
typedef unsigned int uint_t;

#define NFRAMES 8
#define HD 32
#define CDIM 384
#define NH 12
#define NTOK 2048
#define QKCOLS 768
#define TILEB 2048  // one 32-row fragment tile = 128 slots * 16B
// (1/sqrt(32)) * log2(e): fold softmax scale AND exp2 base-change into Wq
#define QSCALE 0.2550541213313367f

static __device__ __forceinline__ ushort_t f2bf(float f) {
    __hip_bfloat16 h = __float2bfloat16(f);
    return *reinterpret_cast<ushort_t*>(&h);
}
static __device__ __forceinline__ uint_t packbf2(float lo, float hi) {
    return (uint_t)f2bf(lo) | ((uint_t)f2bf(hi) << 16);
}

// ---------------- fused pack: x -> Xt + VFG + psum ; qk_w -> Wb ----------------
__global__ __launch_bounds__(256) void pack_kernel(const float* __restrict__ x,
                                                   const float* __restrict__ qk_w,
                                                   ushort_t* __restrict__ Xt,
                                                   ushort_t* __restrict__ VFG,
                                                   float* __restrict__ psum,
                                                   ushort_t* __restrict__ Wb) {
    int tid = threadIdx.x;
    int bid = blockIdx.x;
    if (bid >= 192) {
        int vid = (bid - 192) * 256 + tid;  // 0..36863
        int j = vid / 48;                   // output row 0..767
        float scale = (j < CDIM) ? QSCALE : 1.0f;
        const float* src = qk_w + vid * 8;
        float4 a = *(const float4*)src;
        float4 b = *(const float4*)(src + 4);
        uint4 o = make_uint4(packbf2(a.x * scale, a.y * scale), packbf2(a.z * scale, a.w * scale),
                             packbf2(b.x * scale, b.y * scale), packbf2(b.z * scale, b.w * scale));
        *(uint4*)(Wb + vid * 8) = o;
        return;
    }
    __shared__ float lds[32 * 257];
    __shared__ float red[8][32];
    int bt = bid & 15;  // b*8 + t
    int h = bid >> 4;   // head
    int c0 = h * 32;
    const float* src = x + ((long)bt * CDIM + c0) * 256;
#pragma unroll
    for (int i = 0; i < 32; ++i) lds[i * 257 + tid] = src[i * 256 + tid];
    __syncthreads();
    int b = bt >> 3, t = bt & 7;
    long n = (long)b * NTOK + t * 256 + tid;
    uint4* dst = reinterpret_cast<uint4*>(Xt + n * CDIM + c0);
#pragma unroll
    for (int k = 0; k < 4; ++k) {
        uint_t vv[4];
#pragma unroll
        for (int q = 0; q < 4; ++q)
            vv[q] = packbf2(lds[(k * 8 + q * 2) * 257 + tid], lds[(k * 8 + q * 2 + 1) * 257 + tid]);
        dst[k] = make_uint4(vv[0], vv[1], vv[2], vv[3]);
    }
    int bh = b * NH + h;
#pragma unroll
    for (int pass = 0; pass < 4; ++pass) {
        int kt = pass * 2 + (tid >> 7);
        int slot = tid & 127;
        int d = slot & 31, c2 = slot >> 5;
        const float* p0 = &lds[d * 257 + kt * 32 + c2 * 8];
        uint4 o = make_uint4(packbf2(p0[0], p0[1]), packbf2(p0[2], p0[3]),
                             packbf2(p0[4], p0[5]), packbf2(p0[6], p0[7]));
        *(uint4*)((char*)VFG + ((size_t)(bh * 64 + t * 8 + kt)) * TILEB + slot * 16) = o;
    }
    int ch = tid & 31, seg = tid >> 5;
    float s = 0.f;
#pragma unroll
    for (int j = 0; j < 32; ++j) s += lds[ch * 257 + seg * 32 + j];
    red[seg][ch] = s;
    __syncthreads();
    if (tid < 32) {
        float tot = 0.f;
#pragma unroll
        for (int i = 0; i < 8; ++i) tot += red[i][tid];
        psum[(bt * NH + h) * HD + tid] = tot;
    }
}

// ---------------- projection (32x32x16 MFMA): Q/K emitted as fragment tiles ----------------
__global__ __launch_bounds__(256) void proj_kernel(const ushort_t* __restrict__ Xt,
                                                   const ushort_t* __restrict__ Wb,
                                                   ushort_t* __restrict__ QFG,
                                                   ushort_t* __restrict__ KFG) {
    __shared__ __align__(16) ushort_t tb[4][32][40];
    int tid = threadIdx.x;
    int lane = tid & 63;
    int w = tid >> 6;
    int wid = blockIdx.x * 4 + w;
    int mb = wid / 24, nb = wid % 24;
    int j31 = lane & 31, hi = lane >> 5;
    const char* Arow = (const char*)(Xt + (mb * 32 + j31) * CDIM + hi * 8);
    const char* Brow = (const char*)(Wb + (nb * 32 + j31) * CDIM + hi * 8);
    f32x16 acc = {};
#pragma unroll
    for (int k16 = 0; k16 < 24; ++k16) {
        short8 a = *(const short8*)(Arow + k16 * 32);
        short8 bb = *(const short8*)(Brow + k16 * 32);
        acc = __builtin_amdgcn_mfma_f32_32x32x16_bf16(a, bb, acc, 0, 0, 0);
    }
#pragma unroll
    for (int q = 0; q < 16; ++q) {
        int row = (q & 3) + 8 * (q >> 2) + 4 * hi;
        tb[w][row][j31] = f2bf(acc[q]);
    }
    short8 f0 = *(const short8*)&tb[w][j31][hi * 8];
    short8 f1 = *(const short8*)&tb[w][j31][16 + hi * 8];
    int bsel = mb >> 6;
    int tile = mb & 63;
    int hh = (nb < 12) ? nb : nb - 12;
    ushort_t* dstbuf = (nb < 12) ? QFG : KFG;
    char* base = (char*)dstbuf + ((size_t)((bsel * NH + hh) * 64 + tile)) * TILEB;
    *(short8*)(base + lane * 16) = f0;
    *(short8*)(base + 1024 + lane * 16) = f1;
}

// ---------------- attention (production, unchanged from round 10) ----------------
__global__ __launch_bounds__(256) void attn_kernel(
    const ushort_t* __restrict__ QFG, const ushort_t* __restrict__ KFG,
    const ushort_t* __restrict__ VFG, const float* __restrict__ x,
    const float* __restrict__ psum, const float* __restrict__ alpha,
    const float* __restrict__ beta, const float* __restrict__ gamma,
    float* __restrict__ out) {
    __shared__ float mrg[3 * 1088 + 32];

    int tid = threadIdx.x, lane = tid & 63, w = tid >> 6;
    int bid = blockIdx.x;
    int L = (bid & 7) * 192 + (bid >> 3);  // XCD swizzle, 1536 = 8*192, bijective
    int qc = L & 63, bh = L >> 6;
    int h = bh % NH, b = bh / NH;
    int j31 = lane & 31, hi = lane >> 5;
    int qb = qc * 32;

    const char* Qb = (const char*)QFG + ((size_t)(bh * 64 + qc)) * TILEB + lane * 16;
    short8 qf0 = *(const short8*)(Qb);
    short8 qf1 = *(const short8*)(Qb + 1024);

    const char* Kbase = (const char*)KFG + ((size_t)(bh * 64 + w * 16)) * TILEB + lane * 16;
    const char* Vbase = (const char*)VFG + ((size_t)(bh * 64 + w * 16)) * TILEB + lane * 16;

    f32x16 acc = {};
    f32x2 lp2 = {};

    short8 K0a, K1a, V0a, V1a, K0b, K1b, V0b, V1b;
    f32x16 sA, sB;

#define LK(i, K0, K1)                              \
    {                                              \
        size_t off = (size_t)(i)*TILEB;            \
        K0 = *(const short8*)(Kbase + off);        \
        K1 = *(const short8*)(Kbase + off + 1024); \
    }
#define LV(i, V0, V1)                              \
    {                                              \
        size_t off = (size_t)(i)*TILEB;            \
        V0 = *(const short8*)(Vbase + off);        \
        V1 = *(const short8*)(Vbase + off + 1024); \
    }
#define QKM(K0, K1, sdst)                                                      \
    {                                                                          \
        f32x16 t0 = {};                                                        \
        __builtin_amdgcn_s_setprio(1);                                         \
        t0 = __builtin_amdgcn_mfma_f32_32x32x16_bf16(K0, qf0, t0, 0, 0, 0);    \
        sdst = __builtin_amdgcn_mfma_f32_32x32x16_bf16(K1, qf1, t0, 0, 0, 0);  \
        __builtin_amdgcn_s_setprio(0);                                         \
    }
#define SMPV(sv, V0, V1)                                                            \
    {                                                                               \
        uint_t pk[8];                                                               \
        _Pragma("unroll")                                                           \
        for (int j = 0; j < 8; ++j) {                                               \
            float e0 = __builtin_amdgcn_exp2f(sv[2 * j]);                           \
            float e1 = __builtin_amdgcn_exp2f(sv[2 * j + 1]);                       \
            f32x2 ee;                                                               \
            ee[0] = e0;                                                             \
            ee[1] = e1;                                                             \
            lp2 += ee;                                                              \
            asm("v_cvt_pk_bf16_f32 %0, %1, %2" : "=v"(pk[j]) : "v"(e0), "v"(e1));   \
        }                                                                           \
        _Pragma("unroll")                                                           \
        for (int kh = 0; kh < 2; ++kh) {                                            \
            uint_t o0 = pk[kh * 4], o1 = pk[kh * 4 + 1];                            \
            uint_t o2 = pk[kh * 4 + 2], o3 = pk[kh * 4 + 3];                        \
            auto r02 = __builtin_amdgcn_permlane32_swap(o2, o0, false, false);      \
            auto r13 = __builtin_amdgcn_permlane32_swap(o3, o1, false, false);      \
            uint4v uu;                                                              \
            uu[0] = r02[1];                                                         \
            uu[1] = r13[1];                                                         \
            uu[2] = r02[0];                                                         \
            uu[3] = r13[0];                                                         \
            short8 pa = __builtin_bit_cast(short8, uu);                             \
            __builtin_amdgcn_s_setprio(1);                                          \
            acc = __builtin_amdgcn_mfma_f32_32x32x16_bf16(pa, (kh ? V1 : V0), acc, 0, 0, 0); \
            __builtin_amdgcn_s_setprio(0);                                          \
        }                                                                           \
    }

    LK(0, K0a, K1a)
    QKM(K0a, K1a, sA)
    LK(1, K0b, K1b)
    LV(0, V0a, V1a)

#pragma unroll
    for (int i2 = 0; i2 < 7; ++i2) {
        int t = 2 * i2 + 1;
        QKM(K0b, K1b, sB)
        LK(t + 1, K0a, K1a)
        LV(t, V0b, V1b)
        SMPV(sA, V0a, V1a)
        QKM(K0a, K1a, sA)
        LK(t + 2, K0b, K1b)
        LV(t + 1, V0a, V1a)
        SMPV(sB, V0b, V1b)
    }
    QKM(K0b, K1b, sB)
    LV(15, V0b, V1b)
    SMPV(sA, V0a, V1a)
    SMPV(sB, V0b, V1b)

#undef LK
#undef LV
#undef QKM
#undef SMPV

    float lp = lp2[0] + lp2[1];

    if (w) {
        float* ab = mrg + (w - 1) * 1088;
#pragma unroll
        for (int q = 0; q < 16; ++q) ab[lane * 17 + q] = acc[q];
        ab[lane * 17 + 16] = lp;
    }
    __syncthreads();
    if (w == 0) {
#pragma unroll
        for (int q = 0; q < 16; ++q)
            acc[q] += mrg[lane * 17 + q] + mrg[1088 + lane * 17 + q] + mrg[2176 + lane * 17 + q];
        float lsum = lp + mrg[lane * 17 + 16] + mrg[1088 + lane * 17 + 16] + mrg[2176 + lane * 17 + 16];
        lsum += __shfl_xor(lsum, 32);
        float* Lb = mrg + 3 * 1088;
        if (!hi) Lb[j31] = lsum;
        float alpha_h = alpha[h], beta_h = beta[h], gamma_h = gamma[h];
        int d = j31, c = h * HD + d;
        float sv = 0.f;
#pragma unroll
        for (int t = 0; t < NFRAMES; ++t) sv += psum[((b * NFRAMES + t) * NH + h) * HD + d];
        float gsv = gamma_h * sv * (1.0f / NTOK);
#pragma unroll
        for (int q = 0; q < 16; ++q) {
            int qrow = (q & 3) + 8 * (q >> 2) + 4 * hi;
            int n = qb + qrow;
            float linv = 1.0f / Lb[qrow];
            long xidx = ((long)(b * NFRAMES + (n >> 8)) * CDIM + c) * 256 + (n & 255);
            out[xidx] = beta_h * acc[q] * linv + alpha_h * x[xidx] - gsv;
        }
    }
}

// ---------------- DIAGNOSTIC: skeleton-only ablation (loads + QK + stand-in PV, no softmax) ----------------
// Same grid/waves/load-pattern/MFMA-count as production. Softmax chain replaced by keepalives.
// Launched 8x so its duration & counters are unambiguous: T_noSM = (total - 54.4us)/8.
__global__ __launch_bounds__(256) void attn_noSM(
    const ushort_t* __restrict__ QFG, const ushort_t* __restrict__ KFG,
    const ushort_t* __restrict__ VFG) {
    int tid = threadIdx.x, lane = tid & 63, w = tid >> 6;
    int bid = blockIdx.x;
    int L = (bid & 7) * 192 + (bid >> 3);
    int qc = L & 63, bh = L >> 6;
    const char* Qb = (const char*)QFG + ((size_t)(bh * 64 + qc)) * TILEB + lane * 16;
    short8 qf0 = *(const short8*)(Qb);
    short8 qf1 = *(const short8*)(Qb + 1024);
    const char* Kbase = (const char*)KFG + ((size_t)(bh * 64 + w * 16)) * TILEB + lane * 16;
    const char* Vbase = (const char*)VFG + ((size_t)(bh * 64 + w * 16)) * TILEB + lane * 16;
    f32x16 acc = {};
#pragma unroll
    for (int i = 0; i < 16; ++i) {
        size_t off = (size_t)i * TILEB;
        short8 K0 = *(const short8*)(Kbase + off);
        short8 K1 = *(const short8*)(Kbase + off + 1024);
        short8 V0 = *(const short8*)(Vbase + off);
        short8 V1 = *(const short8*)(Vbase + off + 1024);
        f32x16 s = {};
        __builtin_amdgcn_s_setprio(1);
        s = __builtin_amdgcn_mfma_f32_32x32x16_bf16(K0, qf0, s, 0, 0, 0);
        s = __builtin_amdgcn_mfma_f32_32x32x16_bf16(K1, qf1, s, 0, 0, 0);
        __builtin_amdgcn_s_setprio(0);
        asm volatile("" ::"v"(s[0]), "v"(s[7]), "v"(s[15]));  // keep QK alive (rule 17)
        __builtin_amdgcn_s_setprio(1);
        acc = __builtin_amdgcn_mfma_f32_32x32x16_bf16(K0, V0, acc, 0, 0, 0);  // stand-in PV
        acc = __builtin_amdgcn_mfma_f32_32x32x16_bf16(K1, V1, acc, 0, 0, 0);
        __builtin_amdgcn_s_setprio(0);
    }
    asm volatile("" ::"v"(acc[0]), "v"(acc[7]), "v"(acc[15]));
}

extern "C" void kernel_launch(void* const* d_in, const int* in_sizes, int n_in,
                              void* d_out, int out_size, void* d_ws, size_t ws_size,
                              hipStream_t stream) {
    const float* x = (const float*)d_in[0];
    const float* qk_w = (const float*)d_in[1];
    const float* alpha = (const float*)d_in[2];
    const float* beta = (const float*)d_in[3];
    const float* gamma = (const float*)d_in[4];
    float* out = (float*)d_out;

    char* ws = (char*)d_ws;
    ushort_t* Xt = (ushort_t*)ws;                    // 3,145,728
    ushort_t* Wb = (ushort_t*)(ws + 3145728);        // 589,824
    ushort_t* QFG = (ushort_t*)(ws + 3735552);       // 3,145,728
    ushort_t* KFG = (ushort_t*)(ws + 6881280);       // 3,145,728
    ushort_t* VFG = (ushort_t*)(ws + 10027008);      // 3,145,728
    float* psum = (float*)(ws + 13172736);           // 24,576

    hipLaunchKernelGGL(pack_kernel, dim3(336), dim3(256), 0, stream, x, qk_w, Xt, VFG, psum, Wb);
    hipLaunchKernelGGL(proj_kernel, dim3(768), dim3(256), 0, stream, Xt, Wb, QFG, KFG);
    hipLaunchKernelGGL(attn_kernel, dim3(1536), dim3(256), 0, stream,
                       QFG, KFG, VFG, x, psum, alpha, beta, gamma, out);
    // --- diagnostic: 8 replicas of the skeleton ablation (write nothing) ---
    for (int r = 0; r < 8; ++r)
        hipLaunchKernelGGL(attn_noSM, dim3(1536), dim3(256), 0, stream, QFG, KFG, VFG);
}

// Round 12
// 61.861 us; speedup vs baseline: 2.7624x; 2.7624x over previous
//
#include <hip/hip_runtime.h>
#include <hip/hip_bf16.h>

typedef __attribute__((ext_vector_type(8))) short short8;
typedef __attribute__((ext_vector_type(2))) float f32x2;
typedef __attribute__((ext_vector_type(16))) float f32x16;
typedef __attribute__((ext_vector_type(4))) unsigned int uint4v;
typedef unsigned short ushort_t;
typedef unsigned int uint_t;

#define NFRAMES 8
#define HD 32
#define CDIM 384
#define NH 12
#define NTOK 2048
#define QKCOLS 768
#define TILEB 2048  // one 32-row fragment tile = 128 slots * 16B
// (1/sqrt(32)) * log2(e): fold softmax scale AND exp2 base-change into Wq
#define QSCALE 0.2550541213313367f

static __device__ __forceinline__ ushort_t f2bf(float f) {
    __hip_bfloat16 h = __float2bfloat16(f);
    return *reinterpret_cast<ushort_t*>(&h);
}
static __device__ __forceinline__ uint_t packbf2(float lo, float hi) {
    return (uint_t)f2bf(lo) | ((uint_t)f2bf(hi) << 16);
}
// full-rate VALU exp2: magic-round + cubic poly + exponent add. rel err ~6e-4.
// valid for |x| < ~30 (our s in [-10, 2]); no trans-pipe use.
static __device__ __forceinline__ float exp2_valu(float xx) {
    float t0 = xx + 12582912.0f;  // 1.5*2^23: RNE integer round in the mantissa
    int nn = __builtin_bit_cast(int, t0) - 0x4B400000;
    float ff = xx - (t0 - 12582912.0f);  // frac in [-0.5, 0.5]
    float pp = __builtin_fmaf(
        ff, __builtin_fmaf(ff, __builtin_fmaf(ff, 0.0558282f, 0.2401530f), 0.6931472f), 1.0f);
    return __builtin_bit_cast(float, __builtin_bit_cast(int, pp) + (int)((unsigned)nn << 23));
}

// ---------------- fused pack: x -> Xt + VFG + psum ; qk_w -> Wb ----------------
__global__ __launch_bounds__(256) void pack_kernel(const float* __restrict__ x,
                                                   const float* __restrict__ qk_w,
                                                   ushort_t* __restrict__ Xt,
                                                   ushort_t* __restrict__ VFG,
                                                   float* __restrict__ psum,
                                                   ushort_t* __restrict__ Wb) {
    int tid = threadIdx.x;
    int bid = blockIdx.x;
    if (bid >= 192) {
        int vid = (bid - 192) * 256 + tid;  // 0..36863
        int j = vid / 48;                   // output row 0..767
        float scale = (j < CDIM) ? QSCALE : 1.0f;
        const float* src = qk_w + vid * 8;
        float4 a = *(const float4*)src;
        float4 b = *(const float4*)(src + 4);
        uint4 o = make_uint4(packbf2(a.x * scale, a.y * scale), packbf2(a.z * scale, a.w * scale),
                             packbf2(b.x * scale, b.y * scale), packbf2(b.z * scale, b.w * scale));
        *(uint4*)(Wb + vid * 8) = o;
        return;
    }
    __shared__ float lds[32 * 257];
    __shared__ float red[8][32];
    int bt = bid & 15;  // b*8 + t
    int h = bid >> 4;   // head
    int c0 = h * 32;
    const float* src = x + ((long)bt * CDIM + c0) * 256;
#pragma unroll
    for (int i = 0; i < 32; ++i) lds[i * 257 + tid] = src[i * 256 + tid];
    __syncthreads();
    int b = bt >> 3, t = bt & 7;
    long n = (long)b * NTOK + t * 256 + tid;
    uint4* dst = reinterpret_cast<uint4*>(Xt + n * CDIM + c0);
#pragma unroll
    for (int k = 0; k < 4; ++k) {
        uint_t vv[4];
#pragma unroll
        for (int q = 0; q < 4; ++q)
            vv[q] = packbf2(lds[(k * 8 + q * 2) * 257 + tid], lds[(k * 8 + q * 2 + 1) * 257 + tid]);
        dst[k] = make_uint4(vv[0], vv[1], vv[2], vv[3]);
    }
    int bh = b * NH + h;
#pragma unroll
    for (int pass = 0; pass < 4; ++pass) {
        int kt = pass * 2 + (tid >> 7);
        int slot = tid & 127;
        int d = slot & 31, c2 = slot >> 5;
        const float* p0 = &lds[d * 257 + kt * 32 + c2 * 8];
        uint4 o = make_uint4(packbf2(p0[0], p0[1]), packbf2(p0[2], p0[3]),
                             packbf2(p0[4], p0[5]), packbf2(p0[6], p0[7]));
        *(uint4*)((char*)VFG + ((size_t)(bh * 64 + t * 8 + kt)) * TILEB + slot * 16) = o;
    }
    int ch = tid & 31, seg = tid >> 5;
    float s = 0.f;
#pragma unroll
    for (int j = 0; j < 32; ++j) s += lds[ch * 257 + seg * 32 + j];
    red[seg][ch] = s;
    __syncthreads();
    if (tid < 32) {
        float tot = 0.f;
#pragma unroll
        for (int i = 0; i < 8; ++i) tot += red[i][tid];
        psum[(bt * NH + h) * HD + tid] = tot;
    }
}

// ---------------- projection (32x32x16 MFMA): Q/K emitted as fragment tiles ----------------
__global__ __launch_bounds__(256) void proj_kernel(const ushort_t* __restrict__ Xt,
                                                   const ushort_t* __restrict__ Wb,
                                                   ushort_t* __restrict__ QFG,
                                                   ushort_t* __restrict__ KFG) {
    __shared__ __align__(16) ushort_t tb[4][32][40];
    int tid = threadIdx.x;
    int lane = tid & 63;
    int w = tid >> 6;
    int wid = blockIdx.x * 4 + w;
    int mb = wid / 24, nb = wid % 24;
    int j31 = lane & 31, hi = lane >> 5;
    const char* Arow = (const char*)(Xt + (mb * 32 + j31) * CDIM + hi * 8);
    const char* Brow = (const char*)(Wb + (nb * 32 + j31) * CDIM + hi * 8);
    f32x16 acc = {};
#pragma unroll
    for (int k16 = 0; k16 < 24; ++k16) {
        short8 a = *(const short8*)(Arow + k16 * 32);
        short8 bb = *(const short8*)(Brow + k16 * 32);
        acc = __builtin_amdgcn_mfma_f32_32x32x16_bf16(a, bb, acc, 0, 0, 0);
    }
#pragma unroll
    for (int q = 0; q < 16; ++q) {
        int row = (q & 3) + 8 * (q >> 2) + 4 * hi;
        tb[w][row][j31] = f2bf(acc[q]);
    }
    short8 f0 = *(const short8*)&tb[w][j31][hi * 8];
    short8 f1 = *(const short8*)&tb[w][j31][16 + hi * 8];
    int bsel = mb >> 6;
    int tile = mb & 63;
    int hh = (nb < 12) ? nb : nb - 12;
    ushort_t* dstbuf = (nb < 12) ? QFG : KFG;
    char* base = (char*)dstbuf + ((size_t)((bsel * NH + hh) * 64 + tile)) * TILEB;
    *(short8*)(base + lane * 16) = f0;
    *(short8*)(base + 1024 + lane * 16) = f1;
}

// ---------------- attention: att[2] pipeline, VALU-only softmax, no setprio ----------------
// grid 1536 = 24 bh * 64 q-tiles(32q). 4 waves/block = 4 kv-quarters of 16 tiles (32 kv each).
__global__ __launch_bounds__(256) void attn_kernel(
    const ushort_t* __restrict__ QFG, const ushort_t* __restrict__ KFG,
    const ushort_t* __restrict__ VFG, const float* __restrict__ x,
    const float* __restrict__ psum, const float* __restrict__ alpha,
    const float* __restrict__ beta, const float* __restrict__ gamma,
    float* __restrict__ out) {
    __shared__ float mrg[3 * 1088 + 32];

    int tid = threadIdx.x, lane = tid & 63, w = tid >> 6;
    int bid = blockIdx.x;
    int L = (bid & 7) * 192 + (bid >> 3);  // XCD swizzle, 1536 = 8*192, bijective
    int qc = L & 63, bh = L >> 6;
    int h = bh % NH, b = bh / NH;
    int j31 = lane & 31, hi = lane >> 5;
    int qb = qc * 32;

    const char* Qb = (const char*)QFG + ((size_t)(bh * 64 + qc)) * TILEB + lane * 16;
    short8 qf0 = *(const short8*)(Qb);
    short8 qf1 = *(const short8*)(Qb + 1024);

    const char* Kbase = (const char*)KFG + ((size_t)(bh * 64 + w * 16)) * TILEB + lane * 16;
    const char* Vbase = (const char*)VFG + ((size_t)(bh * 64 + w * 16)) * TILEB + lane * 16;

    f32x16 acc = {};
    f32x2 lp2 = {};

    short8 K0a, K1a, V0a, V1a, K0b, K1b, V0b, V1b;
    f32x16 sA, sB;

#define LK(i, K0, K1)                              \
    {                                              \
        size_t off = (size_t)(i)*TILEB;            \
        K0 = *(const short8*)(Kbase + off);        \
        K1 = *(const short8*)(Kbase + off + 1024); \
    }
#define LV(i, V0, V1)                              \
    {                                              \
        size_t off = (size_t)(i)*TILEB;            \
        V0 = *(const short8*)(Vbase + off);        \
        V1 = *(const short8*)(Vbase + off + 1024); \
    }
#define QKM(K0, K1, sdst)                                                      \
    {                                                                          \
        f32x16 t0 = {};                                                        \
        t0 = __builtin_amdgcn_mfma_f32_32x32x16_bf16(K0, qf0, t0, 0, 0, 0);    \
        sdst = __builtin_amdgcn_mfma_f32_32x32x16_bf16(K1, qf1, t0, 0, 0, 0);  \
    }
#define SMPV(sv, V0, V1)                                                            \
    {                                                                               \
        uint_t pk[8];                                                               \
        _Pragma("unroll")                                                           \
        for (int j = 0; j < 8; ++j) {                                               \
            float e0 = exp2_valu(sv[2 * j]);                                        \
            float e1 = exp2_valu(sv[2 * j + 1]);                                    \
            f32x2 ee;                                                               \
            ee[0] = e0;                                                             \
            ee[1] = e1;                                                             \
            lp2 += ee;                                                              \
            asm("v_cvt_pk_bf16_f32 %0, %1, %2" : "=v"(pk[j]) : "v"(e0), "v"(e1));   \
        }                                                                           \
        _Pragma("unroll")                                                           \
        for (int kh = 0; kh < 2; ++kh) {                                            \
            uint_t o0 = pk[kh * 4], o1 = pk[kh * 4 + 1];                            \
            uint_t o2 = pk[kh * 4 + 2], o3 = pk[kh * 4 + 3];                        \
            auto r02 = __builtin_amdgcn_permlane32_swap(o2, o0, false, false);      \
            auto r13 = __builtin_amdgcn_permlane32_swap(o3, o1, false, false);      \
            uint4v uu;                                                              \
            uu[0] = r02[1];                                                         \
            uu[1] = r13[1];                                                         \
            uu[2] = r02[0];                                                         \
            uu[3] = r13[0];                                                         \
            short8 pa = __builtin_bit_cast(short8, uu);                             \
            acc = __builtin_amdgcn_mfma_f32_32x32x16_bf16(pa, (kh ? V1 : V0), acc, 0, 0, 0); \
        }                                                                           \
    }

    LK(0, K0a, K1a)
    QKM(K0a, K1a, sA)
    LK(1, K0b, K1b)
    LV(0, V0a, V1a)

#pragma unroll
    for (int i2 = 0; i2 < 7; ++i2) {
        int t = 2 * i2 + 1;
        QKM(K0b, K1b, sB)
        LK(t + 1, K0a, K1a)
        LV(t, V0b, V1b)
        SMPV(sA, V0a, V1a)
        QKM(K0a, K1a, sA)
        LK(t + 2, K0b, K1b)
        LV(t + 1, V0a, V1a)
        SMPV(sB, V0b, V1b)
    }
    QKM(K0b, K1b, sB)
    LV(15, V0b, V1b)
    SMPV(sA, V0a, V1a)
    SMPV(sB, V0b, V1b)

#undef LK
#undef LV
#undef QKM
#undef SMPV

    float lp = lp2[0] + lp2[1];

    if (w) {
        float* ab = mrg + (w - 1) * 1088;
#pragma unroll
        for (int q = 0; q < 16; ++q) ab[lane * 17 + q] = acc[q];
        ab[lane * 17 + 16] = lp;
    }
    __syncthreads();
    if (w == 0) {
#pragma unroll
        for (int q = 0; q < 16; ++q)
            acc[q] += mrg[lane * 17 + q] + mrg[1088 + lane * 17 + q] + mrg[2176 + lane * 17 + q];
        float lsum = lp + mrg[lane * 17 + 16] + mrg[1088 + lane * 17 + 16] + mrg[2176 + lane * 17 + 16];
        lsum += __shfl_xor(lsum, 32);
        float* Lb = mrg + 3 * 1088;
        if (!hi) Lb[j31] = lsum;
        float alpha_h = alpha[h], beta_h = beta[h], gamma_h = gamma[h];
        int d = j31, c = h * HD + d;
        float sv = 0.f;
#pragma unroll
        for (int t = 0; t < NFRAMES; ++t) sv += psum[((b * NFRAMES + t) * NH + h) * HD + d];
        float gsv = gamma_h * sv * (1.0f / NTOK);
#pragma unroll
        for (int q = 0; q < 16; ++q) {
            int qrow = (q & 3) + 8 * (q >> 2) + 4 * hi;
            int n = qb + qrow;
            float linv = 1.0f / Lb[qrow];
            long xidx = ((long)(b * NFRAMES + (n >> 8)) * CDIM + c) * 256 + (n & 255);
            out[xidx] = beta_h * acc[q] * linv + alpha_h * x[xidx] - gsv;
        }
    }
}

extern "C" void kernel_launch(void* const* d_in, const int* in_sizes, int n_in,
                              void* d_out, int out_size, void* d_ws, size_t ws_size,
                              hipStream_t stream) {
    const float* x = (const float*)d_in[0];
    const float* qk_w = (const float*)d_in[1];
    const float* alpha = (const float*)d_in[2];
    const float* beta = (const float*)d_in[3];
    const float* gamma = (const float*)d_in[4];
    float* out = (float*)d_out;

    char* ws = (char*)d_ws;
    ushort_t* Xt = (ushort_t*)ws;                    // 3,145,728
    ushort_t* Wb = (ushort_t*)(ws + 3145728);        // 589,824
    ushort_t* QFG = (ushort_t*)(ws + 3735552);       // 3,145,728
    ushort_t* KFG = (ushort_t*)(ws + 6881280);       // 3,145,728
    ushort_t* VFG = (ushort_t*)(ws + 10027008);      // 3,145,728
    float* psum = (float*)(ws + 13172736);           // 24,576

    hipLaunchKernelGGL(pack_kernel, dim3(336), dim3(256), 0, stream, x, qk_w, Xt, VFG, psum, Wb);
    hipLaunchKernelGGL(proj_kernel, dim3(768), dim3(256), 0, stream, Xt, Wb, QFG, KFG);
    hipLaunchKernelGGL(attn_kernel, dim3(1536), dim3(256), 0, stream,
                       QFG, KFG, VFG, x, psum, alpha, beta, gamma, out);
}

// Round 13
// 54.295 us; speedup vs baseline: 3.1474x; 1.1394x over previous
//
#include <hip/hip_runtime.h>
#include <hip/hip_bf16.h>

typedef __attribute__((ext_vector_type(8))) short short8;
typedef __attribute__((ext_vector_type(2))) float f32x2;
typedef __attribute__((ext_vector_type(16))) float f32x16;
typedef __attribute__((ext_vector_type(4))) unsigned int uint4v;
typedef unsigned short ushort_t;
typedef unsigned int uint_t;

#define NFRAMES 8
#define HD 32
#define CDIM 384
#define NH 12
#define NTOK 2048
#define QKCOLS 768
#define TILEB 2048  // one 32-row fragment tile = 128 slots * 16B
// (1/sqrt(32)) * log2(e): fold softmax scale AND exp2 base-change into Wq
#define QSCALE 0.2550541213313367f

static __device__ __forceinline__ ushort_t f2bf(float f) {
    __hip_bfloat16 h = __float2bfloat16(f);
    return *reinterpret_cast<ushort_t*>(&h);
}
static __device__ __forceinline__ uint_t packbf2(float lo, float hi) {
    return (uint_t)f2bf(lo) | ((uint_t)f2bf(hi) << 16);
}

// ---------------- fused pack: x -> Xt + VFG + psum ; qk_w -> Wb ----------------
__global__ __launch_bounds__(256) void pack_kernel(const float* __restrict__ x,
                                                   const float* __restrict__ qk_w,
                                                   ushort_t* __restrict__ Xt,
                                                   ushort_t* __restrict__ VFG,
                                                   float* __restrict__ psum,
                                                   ushort_t* __restrict__ Wb) {
    int tid = threadIdx.x;
    int bid = blockIdx.x;
    if (bid >= 192) {
        int vid = (bid - 192) * 256 + tid;  // 0..36863
        int j = vid / 48;                   // output row 0..767
        float scale = (j < CDIM) ? QSCALE : 1.0f;
        const float* src = qk_w + vid * 8;
        float4 a = *(const float4*)src;
        float4 b = *(const float4*)(src + 4);
        uint4 o = make_uint4(packbf2(a.x * scale, a.y * scale), packbf2(a.z * scale, a.w * scale),
                             packbf2(b.x * scale, b.y * scale), packbf2(b.z * scale, b.w * scale));
        *(uint4*)(Wb + vid * 8) = o;
        return;
    }
    __shared__ float lds[32 * 257];
    __shared__ float red[8][32];
    int bt = bid & 15;  // b*8 + t
    int h = bid >> 4;   // head
    int c0 = h * 32;
    const float* src = x + ((long)bt * CDIM + c0) * 256;
#pragma unroll
    for (int i = 0; i < 32; ++i) lds[i * 257 + tid] = src[i * 256 + tid];
    __syncthreads();
    int b = bt >> 3, t = bt & 7;
    long n = (long)b * NTOK + t * 256 + tid;
    uint4* dst = reinterpret_cast<uint4*>(Xt + n * CDIM + c0);
#pragma unroll
    for (int k = 0; k < 4; ++k) {
        uint_t vv[4];
#pragma unroll
        for (int q = 0; q < 4; ++q)
            vv[q] = packbf2(lds[(k * 8 + q * 2) * 257 + tid], lds[(k * 8 + q * 2 + 1) * 257 + tid]);
        dst[k] = make_uint4(vv[0], vv[1], vv[2], vv[3]);
    }
    int bh = b * NH + h;
#pragma unroll
    for (int pass = 0; pass < 4; ++pass) {
        int kt = pass * 2 + (tid >> 7);
        int slot = tid & 127;
        int d = slot & 31, c2 = slot >> 5;
        const float* p0 = &lds[d * 257 + kt * 32 + c2 * 8];
        uint4 o = make_uint4(packbf2(p0[0], p0[1]), packbf2(p0[2], p0[3]),
                             packbf2(p0[4], p0[5]), packbf2(p0[6], p0[7]));
        *(uint4*)((char*)VFG + ((size_t)(bh * 64 + t * 8 + kt)) * TILEB + slot * 16) = o;
    }
    int ch = tid & 31, seg = tid >> 5;
    float s = 0.f;
#pragma unroll
    for (int j = 0; j < 32; ++j) s += lds[ch * 257 + seg * 32 + j];
    red[seg][ch] = s;
    __syncthreads();
    if (tid < 32) {
        float tot = 0.f;
#pragma unroll
        for (int i = 0; i < 8; ++i) tot += red[i][tid];
        psum[(bt * NH + h) * HD + tid] = tot;
    }
}

// ---------------- projection (32x32x16 MFMA): Q/K emitted as fragment tiles ----------------
__global__ __launch_bounds__(256) void proj_kernel(const ushort_t* __restrict__ Xt,
                                                   const ushort_t* __restrict__ Wb,
                                                   ushort_t* __restrict__ QFG,
                                                   ushort_t* __restrict__ KFG) {
    __shared__ __align__(16) ushort_t tb[4][32][40];
    int tid = threadIdx.x;
    int lane = tid & 63;
    int w = tid >> 6;
    int wid = blockIdx.x * 4 + w;
    int mb = wid / 24, nb = wid % 24;
    int j31 = lane & 31, hi = lane >> 5;
    const char* Arow = (const char*)(Xt + (mb * 32 + j31) * CDIM + hi * 8);
    const char* Brow = (const char*)(Wb + (nb * 32 + j31) * CDIM + hi * 8);
    f32x16 acc = {};
#pragma unroll
    for (int k16 = 0; k16 < 24; ++k16) {
        short8 a = *(const short8*)(Arow + k16 * 32);
        short8 bb = *(const short8*)(Brow + k16 * 32);
        acc = __builtin_amdgcn_mfma_f32_32x32x16_bf16(a, bb, acc, 0, 0, 0);
    }
#pragma unroll
    for (int q = 0; q < 16; ++q) {
        int row = (q & 3) + 8 * (q >> 2) + 4 * hi;
        tb[w][row][j31] = f2bf(acc[q]);
    }
    short8 f0 = *(const short8*)&tb[w][j31][hi * 8];
    short8 f1 = *(const short8*)&tb[w][j31][16 + hi * 8];
    int bsel = mb >> 6;
    int tile = mb & 63;
    int hh = (nb < 12) ? nb : nb - 12;
    ushort_t* dstbuf = (nb < 12) ? QFG : KFG;
    char* base = (char*)dstbuf + ((size_t)((bsel * NH + hh) * 64 + tile)) * TILEB;
    *(short8*)(base + lane * 16) = f0;
    *(short8*)(base + 1024 + lane * 16) = f1;
}

// ---------------- attention: 8 waves/block, 8 kv tiles per wave (2x concurrency, half chain) ----------------
// grid 1536 = 24 bh * 64 q-tiles(32q). Block = 512 thr; all 8 waves share one q-tile,
// wave w owns kv tiles [w*8, w*8+8). Tree merge over 4 LDS regions (3 barriers).
__global__ __launch_bounds__(512) void attn_kernel(
    const ushort_t* __restrict__ QFG, const ushort_t* __restrict__ KFG,
    const ushort_t* __restrict__ VFG, const float* __restrict__ x,
    const float* __restrict__ psum, const float* __restrict__ alpha,
    const float* __restrict__ beta, const float* __restrict__ gamma,
    float* __restrict__ out) {
    __shared__ float mrg[4 * 1088 + 32];

    int tid = threadIdx.x, lane = tid & 63, w = tid >> 6;  // w: 0..7
    int bid = blockIdx.x;
    int L = (bid & 7) * 192 + (bid >> 3);  // XCD swizzle, 1536 = 8*192, bijective
    int qc = L & 63, bh = L >> 6;
    int h = bh % NH, b = bh / NH;
    int j31 = lane & 31, hi = lane >> 5;
    int qb = qc * 32;

    const char* Qb = (const char*)QFG + ((size_t)(bh * 64 + qc)) * TILEB + lane * 16;
    short8 qf0 = *(const short8*)(Qb);
    short8 qf1 = *(const short8*)(Qb + 1024);

    const char* Kbase = (const char*)KFG + ((size_t)(bh * 64 + w * 8)) * TILEB + lane * 16;
    const char* Vbase = (const char*)VFG + ((size_t)(bh * 64 + w * 8)) * TILEB + lane * 16;

    f32x16 acc = {};
    f32x2 lp2 = {};

#pragma unroll
    for (int i = 0; i < 8; ++i) {
        size_t off = (size_t)i * TILEB;
        short8 K0 = *(const short8*)(Kbase + off);
        short8 K1 = *(const short8*)(Kbase + off + 1024);
        short8 V0 = *(const short8*)(Vbase + off);
        short8 V1 = *(const short8*)(Vbase + off + 1024);
        f32x16 s = {};
        __builtin_amdgcn_s_setprio(1);
        s = __builtin_amdgcn_mfma_f32_32x32x16_bf16(K0, qf0, s, 0, 0, 0);
        s = __builtin_amdgcn_mfma_f32_32x32x16_bf16(K1, qf1, s, 0, 0, 0);
        __builtin_amdgcn_s_setprio(0);
        uint_t pk[8];
#pragma unroll
        for (int j = 0; j < 8; ++j) {
            float e0 = __builtin_amdgcn_exp2f(s[2 * j]);
            float e1 = __builtin_amdgcn_exp2f(s[2 * j + 1]);
            f32x2 ee;
            ee[0] = e0;
            ee[1] = e1;
            lp2 += ee;
            asm("v_cvt_pk_bf16_f32 %0, %1, %2" : "=v"(pk[j]) : "v"(e0), "v"(e1));  // RNE pack
        }
#pragma unroll
        for (int kh = 0; kh < 2; ++kh) {
            uint_t o0 = pk[kh * 4], o1 = pk[kh * 4 + 1];
            uint_t o2 = pk[kh * 4 + 2], o3 = pk[kh * 4 + 3];
            auto r02 = __builtin_amdgcn_permlane32_swap(o2, o0, false, false);
            auto r13 = __builtin_amdgcn_permlane32_swap(o3, o1, false, false);
            uint4v uu;
            uu[0] = r02[1];
            uu[1] = r13[1];
            uu[2] = r02[0];
            uu[3] = r13[0];
            short8 pa = __builtin_bit_cast(short8, uu);
            __builtin_amdgcn_s_setprio(1);
            acc = __builtin_amdgcn_mfma_f32_32x32x16_bf16(pa, (kh ? V1 : V0), acc, 0, 0, 0);
            __builtin_amdgcn_s_setprio(0);
        }
    }

    float lp = lp2[0] + lp2[1];

    // tree merge of 8 partials over 4 LDS regions (stride 17 floats = conflict-free)
    float* reg = mrg + (w & 3) * 1088;
    if (w < 4) {
#pragma unroll
        for (int q = 0; q < 16; ++q) reg[lane * 17 + q] = acc[q];
        reg[lane * 17 + 16] = lp;
    }
    __syncthreads();
    if (w >= 4) {
#pragma unroll
        for (int q = 0; q < 16; ++q) reg[lane * 17 + q] += acc[q];
        reg[lane * 17 + 16] += lp;
    }
    __syncthreads();
    if (w < 2) {
        float* rb = mrg + (w + 2) * 1088;
#pragma unroll
        for (int q = 0; q < 16; ++q) reg[lane * 17 + q] += rb[lane * 17 + q];
        reg[lane * 17 + 16] += rb[lane * 17 + 16];
    }
    __syncthreads();
    if (w == 0) {
#pragma unroll
        for (int q = 0; q < 16; ++q) acc[q] = mrg[lane * 17 + q] + mrg[1088 + lane * 17 + q];
        float lsum = mrg[lane * 17 + 16] + mrg[1088 + lane * 17 + 16];
        lsum += __shfl_xor(lsum, 32);
        float* Lb = mrg + 4 * 1088;
        if (!hi) Lb[j31] = lsum;
        float alpha_h = alpha[h], beta_h = beta[h], gamma_h = gamma[h];
        int d = j31, c = h * HD + d;
        float sv = 0.f;
#pragma unroll
        for (int t = 0; t < NFRAMES; ++t) sv += psum[((b * NFRAMES + t) * NH + h) * HD + d];
        float gsv = gamma_h * sv * (1.0f / NTOK);
#pragma unroll
        for (int q = 0; q < 16; ++q) {
            int qrow = (q & 3) + 8 * (q >> 2) + 4 * hi;
            int n = qb + qrow;
            float linv = 1.0f / Lb[qrow];
            long xidx = ((long)(b * NFRAMES + (n >> 8)) * CDIM + c) * 256 + (n & 255);
            out[xidx] = beta_h * acc[q] * linv + alpha_h * x[xidx] - gsv;
        }
    }
}

extern "C" void kernel_launch(void* const* d_in, const int* in_sizes, int n_in,
                              void* d_out, int out_size, void* d_ws, size_t ws_size,
                              hipStream_t stream) {
    const float* x = (const float*)d_in[0];
    const float* qk_w = (const float*)d_in[1];
    const float* alpha = (const float*)d_in[2];
    const float* beta = (const float*)d_in[3];
    const float* gamma = (const float*)d_in[4];
    float* out = (float*)d_out;

    char* ws = (char*)d_ws;
    ushort_t* Xt = (ushort_t*)ws;                    // 3,145,728
    ushort_t* Wb = (ushort_t*)(ws + 3145728);        // 589,824
    ushort_t* QFG = (ushort_t*)(ws + 3735552);       // 3,145,728
    ushort_t* KFG = (ushort_t*)(ws + 6881280);       // 3,145,728
    ushort_t* VFG = (ushort_t*)(ws + 10027008);      // 3,145,728
    float* psum = (float*)(ws + 13172736);           // 24,576

    hipLaunchKernelGGL(pack_kernel, dim3(336), dim3(256), 0, stream, x, qk_w, Xt, VFG, psum, Wb);
    hipLaunchKernelGGL(proj_kernel, dim3(768), dim3(256), 0, stream, Xt, Wb, QFG, KFG);
    hipLaunchKernelGGL(attn_kernel, dim3(1536), dim3(512), 0, stream,
                       QFG, KFG, VFG, x, psum, alpha, beta, gamma, out);
}

// Round 14
// 52.355 us; speedup vs baseline: 3.2640x; 1.0370x over previous
//
#include <hip/hip_runtime.h>
#include <hip/hip_bf16.h>

typedef __attribute__((ext_vector_type(8))) short short8;
typedef __attribute__((ext_vector_type(2))) float f32x2;
typedef __attribute__((ext_vector_type(16))) float f32x16;
typedef __attribute__((ext_vector_type(4))) unsigned int uint4v;
typedef unsigned short ushort_t;
typedef unsigned int uint_t;

#define NFRAMES 8
#define HD 32
#define CDIM 384
#define NH 12
#define NTOK 2048
#define QKCOLS 768
#define TILEB 2048  // one 32-row fragment tile = 128 slots * 16B
// (1/sqrt(32)) * log2(e): fold softmax scale AND exp2 base-change into Wq
#define QSCALE 0.2550541213313367f

static __device__ __forceinline__ ushort_t f2bf(float f) {
    __hip_bfloat16 h = __float2bfloat16(f);
    return *reinterpret_cast<ushort_t*>(&h);
}
static __device__ __forceinline__ uint_t packbf2(float lo, float hi) {
    return (uint_t)f2bf(lo) | ((uint_t)f2bf(hi) << 16);
}

// ---------------- fused pack: x -> Xt + VFG + psum ; qk_w -> Wb ----------------
__global__ __launch_bounds__(256) void pack_kernel(const float* __restrict__ x,
                                                   const float* __restrict__ qk_w,
                                                   ushort_t* __restrict__ Xt,
                                                   ushort_t* __restrict__ VFG,
                                                   float* __restrict__ psum,
                                                   ushort_t* __restrict__ Wb) {
    int tid = threadIdx.x;
    int bid = blockIdx.x;
    if (bid >= 192) {
        int vid = (bid - 192) * 256 + tid;  // 0..36863
        int j = vid / 48;                   // output row 0..767
        float scale = (j < CDIM) ? QSCALE : 1.0f;
        const float* src = qk_w + vid * 8;
        float4 a = *(const float4*)src;
        float4 b = *(const float4*)(src + 4);
        uint4 o = make_uint4(packbf2(a.x * scale, a.y * scale), packbf2(a.z * scale, a.w * scale),
                             packbf2(b.x * scale, b.y * scale), packbf2(b.z * scale, b.w * scale));
        *(uint4*)(Wb + vid * 8) = o;
        return;
    }
    __shared__ float lds[32 * 257];
    __shared__ float red[8][32];
    int bt = bid & 15;  // b*8 + t
    int h = bid >> 4;   // head
    int c0 = h * 32;
    const float* src = x + ((long)bt * CDIM + c0) * 256;
#pragma unroll
    for (int i = 0; i < 32; ++i) lds[i * 257 + tid] = src[i * 256 + tid];
    __syncthreads();
    int b = bt >> 3, t = bt & 7;
    long n = (long)b * NTOK + t * 256 + tid;
    uint4* dst = reinterpret_cast<uint4*>(Xt + n * CDIM + c0);
#pragma unroll
    for (int k = 0; k < 4; ++k) {
        uint_t vv[4];
#pragma unroll
        for (int q = 0; q < 4; ++q)
            vv[q] = packbf2(lds[(k * 8 + q * 2) * 257 + tid], lds[(k * 8 + q * 2 + 1) * 257 + tid]);
        dst[k] = make_uint4(vv[0], vv[1], vv[2], vv[3]);
    }
    int bh = b * NH + h;
#pragma unroll
    for (int pass = 0; pass < 4; ++pass) {
        int kt = pass * 2 + (tid >> 7);
        int slot = tid & 127;
        int d = slot & 31, c2 = slot >> 5;
        const float* p0 = &lds[d * 257 + kt * 32 + c2 * 8];
        uint4 o = make_uint4(packbf2(p0[0], p0[1]), packbf2(p0[2], p0[3]),
                             packbf2(p0[4], p0[5]), packbf2(p0[6], p0[7]));
        *(uint4*)((char*)VFG + ((size_t)(bh * 64 + t * 8 + kt)) * TILEB + slot * 16) = o;
    }
    int ch = tid & 31, seg = tid >> 5;
    float s = 0.f;
#pragma unroll
    for (int j = 0; j < 32; ++j) s += lds[ch * 257 + seg * 32 + j];
    red[seg][ch] = s;
    __syncthreads();
    if (tid < 32) {
        float tot = 0.f;
#pragma unroll
        for (int i = 0; i < 8; ++i) tot += red[i][tid];
        psum[(bt * NH + h) * HD + tid] = tot;
    }
}

// ---------------- projection: 64x64 per wave (2x2 subtiles) -> half the L2 panel traffic ----------------
// grid 384 x 128thr (2 waves). wid in [0,768): mb2 = wid/12 (64-row tile), nb2 = wid%12 (64-col tile).
// Per 32x32 subtile, same MFMA order/fragment mapping as before -> bit-identical output.
__global__ __launch_bounds__(128) void proj_kernel(const ushort_t* __restrict__ Xt,
                                                   const ushort_t* __restrict__ Wb,
                                                   ushort_t* __restrict__ QFG,
                                                   ushort_t* __restrict__ KFG) {
    __shared__ __align__(16) ushort_t tb[2][32][40];
    int tid = threadIdx.x;
    int lane = tid & 63;
    int w = tid >> 6;  // 0..1
    int wid = blockIdx.x * 2 + w;
    int mb2 = wid / 12, nb2 = wid % 12;
    int j31 = lane & 31, hi = lane >> 5;
    const char* A0 = (const char*)(Xt + (mb2 * 64 + j31) * CDIM + hi * 8);
    const char* A1 = A0 + 32 * CDIM * 2;
    const char* B0 = (const char*)(Wb + (nb2 * 64 + j31) * CDIM + hi * 8);
    const char* B1 = B0 + 32 * CDIM * 2;
    f32x16 acc00 = {}, acc01 = {}, acc10 = {}, acc11 = {};
#pragma unroll
    for (int k16 = 0; k16 < 24; ++k16) {
        short8 a0 = *(const short8*)(A0 + k16 * 32);
        short8 a1 = *(const short8*)(A1 + k16 * 32);
        short8 b0 = *(const short8*)(B0 + k16 * 32);
        short8 b1 = *(const short8*)(B1 + k16 * 32);
        acc00 = __builtin_amdgcn_mfma_f32_32x32x16_bf16(a0, b0, acc00, 0, 0, 0);
        acc01 = __builtin_amdgcn_mfma_f32_32x32x16_bf16(a0, b1, acc01, 0, 0, 0);
        acc10 = __builtin_amdgcn_mfma_f32_32x32x16_bf16(a1, b0, acc10, 0, 0, 0);
        acc11 = __builtin_amdgcn_mfma_f32_32x32x16_bf16(a1, b1, acc11, 0, 0, 0);
    }
    // 4 subtiles: LDS bounce (wave-private; compiler inserts lgkm waits, no barrier needed)
#pragma unroll
    for (int rr = 0; rr < 2; ++rr) {
#pragma unroll
        for (int cc = 0; cc < 2; ++cc) {
            const f32x16& acc = rr ? (cc ? acc11 : acc10) : (cc ? acc01 : acc00);
#pragma unroll
            for (int q = 0; q < 16; ++q) {
                int row = (q & 3) + 8 * (q >> 2) + 4 * hi;
                tb[w][row][j31] = f2bf(acc[q]);
            }
            short8 f0 = *(const short8*)&tb[w][j31][hi * 8];
            short8 f1 = *(const short8*)&tb[w][j31][16 + hi * 8];
            int mtile = mb2 * 2 + rr;       // 32-row tile index 0..127
            int bsel = mtile >> 6;
            int tile = mtile & 63;
            int hcol = nb2 * 2 + cc;        // 32-col tile index 0..23
            int hh = (hcol < 12) ? hcol : hcol - 12;
            ushort_t* dstbuf = (hcol < 12) ? QFG : KFG;
            char* base = (char*)dstbuf + ((size_t)((bsel * NH + hh) * 64 + tile)) * TILEB;
            *(short8*)(base + lane * 16) = f0;
            *(short8*)(base + 1024 + lane * 16) = f1;
        }
    }
}

// ---------------- attention: 8 waves/block, 8 kv tiles per wave (r13 structure) ----------------
__global__ __launch_bounds__(512) void attn_kernel(
    const ushort_t* __restrict__ QFG, const ushort_t* __restrict__ KFG,
    const ushort_t* __restrict__ VFG, const float* __restrict__ x,
    const float* __restrict__ psum, const float* __restrict__ alpha,
    const float* __restrict__ beta, const float* __restrict__ gamma,
    float* __restrict__ out) {
    __shared__ float mrg[4 * 1088 + 32];

    int tid = threadIdx.x, lane = tid & 63, w = tid >> 6;  // w: 0..7
    int bid = blockIdx.x;
    int L = (bid & 7) * 192 + (bid >> 3);  // XCD swizzle, 1536 = 8*192, bijective
    int qc = L & 63, bh = L >> 6;
    int h = bh % NH, b = bh / NH;
    int j31 = lane & 31, hi = lane >> 5;
    int qb = qc * 32;

    const char* Qb = (const char*)QFG + ((size_t)(bh * 64 + qc)) * TILEB + lane * 16;
    short8 qf0 = *(const short8*)(Qb);
    short8 qf1 = *(const short8*)(Qb + 1024);

    const char* Kbase = (const char*)KFG + ((size_t)(bh * 64 + w * 8)) * TILEB + lane * 16;
    const char* Vbase = (const char*)VFG + ((size_t)(bh * 64 + w * 8)) * TILEB + lane * 16;

    f32x16 acc = {};
    f32x2 lp2 = {};

#pragma unroll
    for (int i = 0; i < 8; ++i) {
        size_t off = (size_t)i * TILEB;
        short8 K0 = *(const short8*)(Kbase + off);
        short8 K1 = *(const short8*)(Kbase + off + 1024);
        short8 V0 = *(const short8*)(Vbase + off);
        short8 V1 = *(const short8*)(Vbase + off + 1024);
        f32x16 s = {};
        __builtin_amdgcn_s_setprio(1);
        s = __builtin_amdgcn_mfma_f32_32x32x16_bf16(K0, qf0, s, 0, 0, 0);
        s = __builtin_amdgcn_mfma_f32_32x32x16_bf16(K1, qf1, s, 0, 0, 0);
        __builtin_amdgcn_s_setprio(0);
        uint_t pk[8];
#pragma unroll
        for (int j = 0; j < 8; ++j) {
            float e0 = __builtin_amdgcn_exp2f(s[2 * j]);
            float e1 = __builtin_amdgcn_exp2f(s[2 * j + 1]);
            f32x2 ee;
            ee[0] = e0;
            ee[1] = e1;
            lp2 += ee;
            pk[j] = packbf2(e0, e1);  // compiler emits cvt_pk (m240: >= hand asm)
        }
#pragma unroll
        for (int kh = 0; kh < 2; ++kh) {
            uint_t o0 = pk[kh * 4], o1 = pk[kh * 4 + 1];
            uint_t o2 = pk[kh * 4 + 2], o3 = pk[kh * 4 + 3];
            auto r02 = __builtin_amdgcn_permlane32_swap(o2, o0, false, false);
            auto r13 = __builtin_amdgcn_permlane32_swap(o3, o1, false, false);
            uint4v uu;
            uu[0] = r02[1];
            uu[1] = r13[1];
            uu[2] = r02[0];
            uu[3] = r13[0];
            short8 pa = __builtin_bit_cast(short8, uu);
            __builtin_amdgcn_s_setprio(1);
            acc = __builtin_amdgcn_mfma_f32_32x32x16_bf16(pa, (kh ? V1 : V0), acc, 0, 0, 0);
            __builtin_amdgcn_s_setprio(0);
        }
    }

    float lp = lp2[0] + lp2[1];

    // tree merge of 8 partials over 4 LDS regions (stride 17 floats = conflict-free)
    float* reg = mrg + (w & 3) * 1088;
    if (w < 4) {
#pragma unroll
        for (int q = 0; q < 16; ++q) reg[lane * 17 + q] = acc[q];
        reg[lane * 17 + 16] = lp;
    }
    __syncthreads();
    if (w >= 4) {
#pragma unroll
        for (int q = 0; q < 16; ++q) reg[lane * 17 + q] += acc[q];
        reg[lane * 17 + 16] += lp;
    }
    __syncthreads();
    if (w < 2) {
        float* rb = mrg + (w + 2) * 1088;
#pragma unroll
        for (int q = 0; q < 16; ++q) reg[lane * 17 + q] += rb[lane * 17 + q];
        reg[lane * 17 + 16] += rb[lane * 17 + 16];
    }
    __syncthreads();
    if (w == 0) {
#pragma unroll
        for (int q = 0; q < 16; ++q) acc[q] = mrg[lane * 17 + q] + mrg[1088 + lane * 17 + q];
        float lsum = mrg[lane * 17 + 16] + mrg[1088 + lane * 17 + 16];
        lsum += __shfl_xor(lsum, 32);
        float* Lb = mrg + 4 * 1088;
        if (!hi) Lb[j31] = lsum;
        float alpha_h = alpha[h], beta_h = beta[h], gamma_h = gamma[h];
        int d = j31, c = h * HD + d;
        float sv = 0.f;
#pragma unroll
        for (int t = 0; t < NFRAMES; ++t) sv += psum[((b * NFRAMES + t) * NH + h) * HD + d];
        float gsv = gamma_h * sv * (1.0f / NTOK);
#pragma unroll
        for (int q = 0; q < 16; ++q) {
            int qrow = (q & 3) + 8 * (q >> 2) + 4 * hi;
            int n = qb + qrow;
            float linv = 1.0f / Lb[qrow];
            long xidx = ((long)(b * NFRAMES + (n >> 8)) * CDIM + c) * 256 + (n & 255);
            out[xidx] = beta_h * acc[q] * linv + alpha_h * x[xidx] - gsv;
        }
    }
}

extern "C" void kernel_launch(void* const* d_in, const int* in_sizes, int n_in,
                              void* d_out, int out_size, void* d_ws, size_t ws_size,
                              hipStream_t stream) {
    const float* x = (const float*)d_in[0];
    const float* qk_w = (const float*)d_in[1];
    const float* alpha = (const float*)d_in[2];
    const float* beta = (const float*)d_in[3];
    const float* gamma = (const float*)d_in[4];
    float* out = (float*)d_out;

    char* ws = (char*)d_ws;
    ushort_t* Xt = (ushort_t*)ws;                    // 3,145,728
    ushort_t* Wb = (ushort_t*)(ws + 3145728);        // 589,824
    ushort_t* QFG = (ushort_t*)(ws + 3735552);       // 3,145,728
    ushort_t* KFG = (ushort_t*)(ws + 6881280);       // 3,145,728
    ushort_t* VFG = (ushort_t*)(ws + 10027008);      // 3,145,728
    float* psum = (float*)(ws + 13172736);           // 24,576

    hipLaunchKernelGGL(pack_kernel, dim3(336), dim3(256), 0, stream, x, qk_w, Xt, VFG, psum, Wb);
    hipLaunchKernelGGL(proj_kernel, dim3(384), dim3(128), 0, stream, Xt, Wb, QFG, KFG);
    hipLaunchKernelGGL(attn_kernel, dim3(1536), dim3(512), 0, stream,
                       QFG, KFG, VFG, x, psum, alpha, beta, gamma, out);
}